// Round 1
// baseline (273.641 us; speedup 1.0000x reference)
//
#include <hip/hip_runtime.h>
#include <hip/hip_bf16.h>

// Problem constants
#define Bsz 16
#define Lsz 512
#define Dsz 768
#define Tsz 12
#define Asz 64
#define N1  1536   // Tsz*Asz*2
#define Msz 8192   // Bsz*Lsz

typedef __bf16 bf16;
typedef bf16 bf16x4 __attribute__((ext_vector_type(4)));
typedef bf16 bf16x8 __attribute__((ext_vector_type(8)));
typedef float f32x4 __attribute__((ext_vector_type(4)));

// ---- prep: fp32 -> bf16 convert of input_feature [8192,768] ----
__global__ void cvt_input_kernel(const float* __restrict__ in, bf16* __restrict__ out) {
    int i = blockIdx.x * blockDim.x + threadIdx.x;   // one thread = 4 elems
    float4 v = ((const float4*)in)[i];
    bf16x4 o;
    o[0] = (bf16)v.x; o[1] = (bf16)v.y; o[2] = (bf16)v.z; o[3] = (bf16)v.w;
    ((bf16x4*)out)[i] = o;
}

// ---- prep: W [768,1536] fp32 -> Wt [1536,768] bf16 (K contiguous per row) ----
__global__ void cvt_w_kernel(const float* __restrict__ W, bf16* __restrict__ Wt) {
    int tid = blockIdx.x * blockDim.x + threadIdx.x;  // N1 * (Dsz/8) threads
    int n  = tid % N1;
    int k0 = (tid / N1) * 8;
    bf16x8 o;
#pragma unroll
    for (int j = 0; j < 8; ++j) o[j] = (bf16)W[(size_t)(k0 + j) * N1 + n];
    *(bf16x8*)(Wt + (size_t)n * Dsz + k0) = o;
}

// ---- GEMM1: X[8192,1536] = Abf @ Wt^T + bias (bf16 in, bf16 out, fp32 acc) ----
// 64x64 tile per block, 4 waves, each wave: 16 rows x 64 cols, mfma 16x16x32.
__global__ __launch_bounds__(256) void gemm1_kernel(
    const bf16* __restrict__ Abf, const bf16* __restrict__ Wt,
    const float* __restrict__ bias, bf16* __restrict__ X) {
    int wave = threadIdx.x >> 6, lane = threadIdx.x & 63;
    int bm = blockIdx.y * 64, bn = blockIdx.x * 64;
    int l15 = lane & 15;
    int kl  = (lane >> 4) * 8;

    const bf16* aptr = Abf + (size_t)(bm + wave * 16 + l15) * Dsz + kl;
    f32x4 acc[4] = {};

    for (int kk = 0; kk < Dsz; kk += 32) {
        bf16x8 af = *(const bf16x8*)(aptr + kk);
#pragma unroll
        for (int ct = 0; ct < 4; ++ct) {
            bf16x8 bfv = *(const bf16x8*)(Wt + (size_t)(bn + ct * 16 + l15) * Dsz + kk + kl);
            acc[ct] = __builtin_amdgcn_mfma_f32_16x16x32_bf16(af, bfv, acc[ct], 0, 0, 0);
        }
    }

    int orow = bm + wave * 16 + (lane >> 4) * 4;   // C/D: row=(lane>>4)*4+r, col=lane&15
#pragma unroll
    for (int ct = 0; ct < 4; ++ct) {
        int col = bn + ct * 16 + l15;
        float bv = bias[col];
#pragma unroll
        for (int r = 0; r < 4; ++r) {
            X[(size_t)(orow + r) * N1 + col] = (bf16)(acc[ct][r] + bv);
        }
    }
}

// ---- RoPE + split: X[8192,1536] -> Qr,Kr [192,512,64] bf16 ----
__global__ void rope_kernel(const bf16* __restrict__ X,
                            bf16* __restrict__ Qr, bf16* __restrict__ Kr) {
    int tid = blockIdx.x * blockDim.x + threadIdx.x;   // Bsz*Lsz*Tsz*Asz threads
    int a  = tid & 63;
    int t  = (tid >> 6) % Tsz;
    int bl = (tid >> 6) / Tsz;          // b*512 + l
    int l  = bl & 511;
    int b  = bl >> 9;

    const bf16* xr = X + (size_t)bl * N1;
    int c1 = (t * 64 + a) * 2;
    float q  = (float)xr[c1],  k  = (float)xr[c1 + 1];
    int  a2  = (a < 32) ? (2 * a + 1) : (2 * (a - 32));
    float sg = (a < 32) ? -1.f : 1.f;
    int  c2  = (t * 64 + a2) * 2;
    float q2 = (float)xr[c2], k2 = (float)xr[c2 + 1];

    // theta = 10000^(-(a>>1)/32) ; pe = l * theta
    float theta = expf(-0.28782313662425575f * (float)(a >> 1));
    float pe = (float)l * theta;
    float s, c;
    sincosf(pe, &s, &c);

    float qo = q * c + sg * q2 * s;
    float ko = k * c + sg * k2 * s;

    size_t oi = ((size_t)(b * Tsz + t) * Lsz + l) * Asz + a;
    Qr[oi] = (bf16)qo;
    Kr[oi] = (bf16)ko;
}

// ---- QK^T + mask: out[b,t,i,j]; 64x64 tile per block ----
__global__ __launch_bounds__(256) void qk_kernel(
    const bf16* __restrict__ Qr, const bf16* __restrict__ Kr,
    const int* __restrict__ mask, float* __restrict__ out) {
    int z = blockIdx.z;               // b*T + t
    int b = z / Tsz;
    int i0 = blockIdx.y * 64, j0 = blockIdx.x * 64;
    float* ob = out + (size_t)z * Lsz * Lsz;

    if (blockIdx.y > blockIdx.x) {
        // fully below diagonal: pure -1e12 fill
        int r  = threadIdx.x >> 2;
        int cs = threadIdx.x & 3;
        float4 f; f.x = f.y = f.z = f.w = -1e12f;
        float4* p = (float4*)(ob + (size_t)(i0 + r) * Lsz + j0 + cs * 16);
        p[0] = f; p[1] = f; p[2] = f; p[3] = f;
        return;
    }

    int wave = threadIdx.x >> 6, lane = threadIdx.x & 63;
    int l15 = lane & 15;
    int kl  = (lane >> 4) * 8;
    const bf16* Qb = Qr + (size_t)z * Lsz * Asz;
    const bf16* Kb = Kr + (size_t)z * Lsz * Asz;

    int qrow = i0 + wave * 16 + l15;
    bf16x8 a0 = *(const bf16x8*)(Qb + (size_t)qrow * 64 + kl);
    bf16x8 a1 = *(const bf16x8*)(Qb + (size_t)qrow * 64 + 32 + kl);

    f32x4 acc[4] = {};
#pragma unroll
    for (int ct = 0; ct < 4; ++ct) {
        int krow = j0 + ct * 16 + l15;
        bf16x8 b0 = *(const bf16x8*)(Kb + (size_t)krow * 64 + kl);
        bf16x8 b1 = *(const bf16x8*)(Kb + (size_t)krow * 64 + 32 + kl);
        acc[ct] = __builtin_amdgcn_mfma_f32_16x16x32_bf16(a0, b0, acc[ct], 0, 0, 0);
        acc[ct] = __builtin_amdgcn_mfma_f32_16x16x32_bf16(a1, b1, acc[ct], 0, 0, 0);
    }

    const int* mb = mask + b * Lsz;
    int row0 = i0 + wave * 16 + (lane >> 4) * 4;
#pragma unroll
    for (int ct = 0; ct < 4; ++ct) {
        int col = j0 + ct * 16 + l15;
        bool mj = mb[col] > 0;
#pragma unroll
        for (int r = 0; r < 4; ++r) {
            int row = row0 + r;
            bool keep = mj && (mb[row] > 0) && (row <= col);
            ob[(size_t)row * Lsz + col] = keep ? acc[ct][r] : -1e12f;
        }
    }
}

extern "C" void kernel_launch(void* const* d_in, const int* in_sizes, int n_in,
                              void* d_out, int out_size, void* d_ws, size_t ws_size,
                              hipStream_t stream) {
    const float* in_f  = (const float*)d_in[0];
    const int*   amask = (const int*)d_in[1];
    const float* W     = (const float*)d_in[2];
    const float* bias  = (const float*)d_in[3];
    float* out = (float*)d_out;

    char* ws = (char*)d_ws;
    bf16* Abf = (bf16*)ws;                                   // 8192*768*2  = 12,582,912 B
    bf16* Wt  = (bf16*)(ws + 12582912);                      // 1536*768*2  =  2,359,296 B
    bf16* X   = (bf16*)(ws + 12582912 + 2359296);            // 8192*1536*2 = 25,165,824 B
    bf16* Qr  = (bf16*)(ws + 40108032);                      // 192*512*64*2 = 12,582,912 B
    bf16* Kr  = (bf16*)(ws + 40108032 + 12582912);           // same

    // prep
    cvt_input_kernel<<<(Msz * Dsz / 4) / 256, 256, 0, stream>>>(in_f, Abf);
    cvt_w_kernel<<<(N1 * (Dsz / 8)) / 256, 256, 0, stream>>>(W, Wt);
    // projection GEMM
    gemm1_kernel<<<dim3(N1 / 64, Msz / 64), 256, 0, stream>>>(Abf, Wt, bias, X);
    // rope + q/k split
    rope_kernel<<<(Bsz * Lsz * Tsz * Asz) / 256, 256, 0, stream>>>(X, Qr, Kr);
    // scores + mask
    qk_kernel<<<dim3(Lsz / 64, Lsz / 64, Bsz * Tsz), 256, 0, stream>>>(Qr, Kr, amask, out);
}

// Round 2
// 145.420 us; speedup vs baseline: 1.8817x; 1.8817x over previous
//
#include <hip/hip_runtime.h>
#include <hip/hip_bf16.h>

// Problem constants
#define Bsz 16
#define Lsz 512
#define Dsz 768
#define Tsz 12
#define Asz 64
#define N1  1536   // Tsz*Asz*2
#define Msz 8192   // Bsz*Lsz

typedef __bf16 bf16;
typedef bf16 bf16x4 __attribute__((ext_vector_type(4)));
typedef bf16 bf16x8 __attribute__((ext_vector_type(8)));
typedef float f32x4 __attribute__((ext_vector_type(4)));

__device__ inline void load_lds16(const bf16* g, bf16* l) {
    __builtin_amdgcn_global_load_lds((const __attribute__((address_space(1))) void*)g,
                                     (__attribute__((address_space(3))) void*)l, 16, 0, 0);
}

// ---- prep: fp32 -> bf16 convert of input_feature [8192,768] ----
__global__ void cvt_input_kernel(const float* __restrict__ in, bf16* __restrict__ out) {
    int i = blockIdx.x * blockDim.x + threadIdx.x;   // one thread = 4 elems
    float4 v = ((const float4*)in)[i];
    bf16x4 o;
    o[0] = (bf16)v.x; o[1] = (bf16)v.y; o[2] = (bf16)v.z; o[3] = (bf16)v.w;
    ((bf16x4*)out)[i] = o;
}

// ---- prep: W [768,1536] fp32 -> Wt [1536,768] bf16 (K contiguous per row) ----
__global__ void cvt_w_kernel(const float* __restrict__ W, bf16* __restrict__ Wt) {
    int tid = blockIdx.x * blockDim.x + threadIdx.x;  // N1 * (Dsz/8) threads
    int n  = tid % N1;
    int k0 = (tid / N1) * 8;
    bf16x8 o;
#pragma unroll
    for (int j = 0; j < 8; ++j) o[j] = (bf16)W[(size_t)(k0 + j) * N1 + n];
    *(bf16x8*)(Wt + (size_t)n * Dsz + k0) = o;
}

// ---- GEMM1: X[8192,1536] = Abf @ Wt^T + bias ----
// m97 structure: 128x128 tile, 4 waves (2x2), 4x4 16x16x32 frags/wave,
// double-buffered LDS via global_load_lds(16B), 2-phase loop.
#define BK 32
__global__ __launch_bounds__(256) void gemm1_kernel(
    const bf16* __restrict__ Abf, const bf16* __restrict__ Wt,
    const float* __restrict__ bias, bf16* __restrict__ X) {
    __shared__ bf16 Asm[2][128 * BK];
    __shared__ bf16 Bsm[2][128 * BK];

    const int tid  = threadIdx.x;
    const int wave = tid >> 6, lane = tid & 63;
    const int bm = blockIdx.y * 128, bn = blockIdx.x * 128;
    const int l15 = lane & 15;
    const int klB = (lane >> 4) * 16;          // byte offset of k-slice in a 32-elem row
    const int wr = (wave >> 1) * 64;           // wave row offset in tile
    const int wc = (wave & 1) * 64;            // wave col offset in tile

    // staging geometry: chunk c in {0,1}: elem off = (c*256+tid)*8
    const int srow0 = tid >> 2;                 // rows 0..63  (chunk 0)
    const int scol  = (tid & 3) * 8;            // k offset

    f32x4 acc[4][4] = {};

#define STAGE(buf, kk)                                                              \
    do {                                                                            \
        load_lds16(Abf + (size_t)(bm + srow0) * Dsz + (kk) + scol,                  \
                   &Asm[buf][srow0 * BK + scol]);                                   \
        load_lds16(Abf + (size_t)(bm + 64 + srow0) * Dsz + (kk) + scol,             \
                   &Asm[buf][(64 + srow0) * BK + scol]);                            \
        load_lds16(Wt + (size_t)(bn + srow0) * Dsz + (kk) + scol,                   \
                   &Bsm[buf][srow0 * BK + scol]);                                   \
        load_lds16(Wt + (size_t)(bn + 64 + srow0) * Dsz + (kk) + scol,              \
                   &Bsm[buf][(64 + srow0) * BK + scol]);                            \
    } while (0)

    STAGE(0, 0);
    __syncthreads();

    int cur = 0;
    const int nsteps = Dsz / BK;   // 24
    for (int t = 0; t < nsteps; ++t) {
        if (t + 1 < nsteps) STAGE(cur ^ 1, (t + 1) * BK);

        bf16x8 af[4], bfr[4];
#pragma unroll
        for (int m = 0; m < 4; ++m)
            af[m] = *(const bf16x8*)((const char*)&Asm[cur][0] + (wr + m * 16 + l15) * (BK * 2) + klB);
#pragma unroll
        for (int n = 0; n < 4; ++n)
            bfr[n] = *(const bf16x8*)((const char*)&Bsm[cur][0] + (wc + n * 16 + l15) * (BK * 2) + klB);

#pragma unroll
        for (int m = 0; m < 4; ++m)
#pragma unroll
            for (int n = 0; n < 4; ++n)
                acc[m][n] = __builtin_amdgcn_mfma_f32_16x16x32_bf16(af[m], bfr[n], acc[m][n], 0, 0, 0);

        __syncthreads();
        cur ^= 1;
    }
#undef STAGE

    // epilogue: C/D layout col=lane&15, row=(lane>>4)*4+r
    const int row0 = bm + wr + (lane >> 4) * 4;
#pragma unroll
    for (int n = 0; n < 4; ++n) {
        const int col = bn + wc + n * 16 + l15;
        const float bv = bias[col];
#pragma unroll
        for (int m = 0; m < 4; ++m) {
#pragma unroll
            for (int r = 0; r < 4; ++r) {
                X[(size_t)(row0 + m * 16 + r) * N1 + col] = (bf16)(acc[m][n][r] + bv);
            }
        }
    }
}

// ---- RoPE + split: X[8192,1536] -> Qr,Kr [192,512,64] bf16 ----
__global__ void rope_kernel(const bf16* __restrict__ X,
                            bf16* __restrict__ Qr, bf16* __restrict__ Kr) {
    int tid = blockIdx.x * blockDim.x + threadIdx.x;   // Bsz*Lsz*Tsz*Asz threads
    int a  = tid & 63;
    int t  = (tid >> 6) % Tsz;
    int bl = (tid >> 6) / Tsz;          // b*512 + l
    int l  = bl & 511;
    int b  = bl >> 9;

    const bf16* xr = X + (size_t)bl * N1;
    int c1 = (t * 64 + a) * 2;
    float q  = (float)xr[c1],  k  = (float)xr[c1 + 1];
    int  a2  = (a < 32) ? (2 * a + 1) : (2 * (a - 32));
    float sg = (a < 32) ? -1.f : 1.f;
    int  c2  = (t * 64 + a2) * 2;
    float q2 = (float)xr[c2], k2 = (float)xr[c2 + 1];

    // theta = 10000^(-(a>>1)/32) ; pe = l * theta
    float theta = expf(-0.28782313662425575f * (float)(a >> 1));
    float pe = (float)l * theta;
    float s, c;
    sincosf(pe, &s, &c);

    float qo = q * c + sg * q2 * s;
    float ko = k * c + sg * k2 * s;

    size_t oi = ((size_t)(b * Tsz + t) * Lsz + l) * Asz + a;
    Qr[oi] = (bf16)qo;
    Kr[oi] = (bf16)ko;
}

// ---- QK^T + mask: out[b,t,i,j]; 64x64 tile per block ----
__global__ __launch_bounds__(256) void qk_kernel(
    const bf16* __restrict__ Qr, const bf16* __restrict__ Kr,
    const int* __restrict__ mask, float* __restrict__ out) {
    int z = blockIdx.z;               // b*T + t
    int b = z / Tsz;
    int i0 = blockIdx.y * 64, j0 = blockIdx.x * 64;
    float* ob = out + (size_t)z * Lsz * Lsz;

    if (blockIdx.y > blockIdx.x) {
        // fully below diagonal: pure -1e12 fill
        int r  = threadIdx.x >> 2;
        int cs = threadIdx.x & 3;
        float4 f; f.x = f.y = f.z = f.w = -1e12f;
        float4* p = (float4*)(ob + (size_t)(i0 + r) * Lsz + j0 + cs * 16);
        p[0] = f; p[1] = f; p[2] = f; p[3] = f;
        return;
    }

    int wave = threadIdx.x >> 6, lane = threadIdx.x & 63;
    int l15 = lane & 15;
    int kl  = (lane >> 4) * 8;
    const bf16* Qb = Qr + (size_t)z * Lsz * Asz;
    const bf16* Kb = Kr + (size_t)z * Lsz * Asz;

    int qrow = i0 + wave * 16 + l15;
    bf16x8 a0 = *(const bf16x8*)(Qb + (size_t)qrow * 64 + kl);
    bf16x8 a1 = *(const bf16x8*)(Qb + (size_t)qrow * 64 + 32 + kl);

    f32x4 acc[4] = {};
#pragma unroll
    for (int ct = 0; ct < 4; ++ct) {
        int krow = j0 + ct * 16 + l15;
        bf16x8 b0 = *(const bf16x8*)(Kb + (size_t)krow * 64 + kl);
        bf16x8 b1 = *(const bf16x8*)(Kb + (size_t)krow * 64 + 32 + kl);
        acc[ct] = __builtin_amdgcn_mfma_f32_16x16x32_bf16(a0, b0, acc[ct], 0, 0, 0);
        acc[ct] = __builtin_amdgcn_mfma_f32_16x16x32_bf16(a1, b1, acc[ct], 0, 0, 0);
    }

    const int* mb = mask + b * Lsz;
    int row0 = i0 + wave * 16 + (lane >> 4) * 4;
#pragma unroll
    for (int ct = 0; ct < 4; ++ct) {
        int col = j0 + ct * 16 + l15;
        bool mj = mb[col] > 0;
#pragma unroll
        for (int r = 0; r < 4; ++r) {
            int row = row0 + r;
            bool keep = mj && (mb[row] > 0) && (row <= col);
            ob[(size_t)row * Lsz + col] = keep ? acc[ct][r] : -1e12f;
        }
    }
}

extern "C" void kernel_launch(void* const* d_in, const int* in_sizes, int n_in,
                              void* d_out, int out_size, void* d_ws, size_t ws_size,
                              hipStream_t stream) {
    const float* in_f  = (const float*)d_in[0];
    const int*   amask = (const int*)d_in[1];
    const float* W     = (const float*)d_in[2];
    const float* bias  = (const float*)d_in[3];
    float* out = (float*)d_out;

    char* ws = (char*)d_ws;
    bf16* Abf = (bf16*)ws;                                   // 8192*768*2  = 12,582,912 B
    bf16* Wt  = (bf16*)(ws + 12582912);                      // 1536*768*2  =  2,359,296 B
    bf16* X   = (bf16*)(ws + 12582912 + 2359296);            // 8192*1536*2 = 25,165,824 B
    bf16* Qr  = (bf16*)(ws + 40108032);                      // 192*512*64*2 = 12,582,912 B
    bf16* Kr  = (bf16*)(ws + 40108032 + 12582912);           // same

    // prep
    cvt_input_kernel<<<(Msz * Dsz / 4) / 256, 256, 0, stream>>>(in_f, Abf);
    cvt_w_kernel<<<(N1 * (Dsz / 8)) / 256, 256, 0, stream>>>(W, Wt);
    // projection GEMM (128x128 tiles)
    gemm1_kernel<<<dim3(N1 / 128, Msz / 128), 256, 0, stream>>>(Abf, Wt, bias, X);
    // rope + q/k split
    rope_kernel<<<(Bsz * Lsz * Tsz * Asz) / 256, 256, 0, stream>>>(X, Qr, Kr);
    // scores + mask
    qk_kernel<<<dim3(Lsz / 64, Lsz / 64, Bsz * Tsz), 256, 0, stream>>>(Qr, Kr, amask, out);
}

// Round 3
// 139.728 us; speedup vs baseline: 1.9584x; 1.0407x over previous
//
#include <hip/hip_runtime.h>
#include <hip/hip_bf16.h>

// Problem constants
#define Bsz 16
#define Lsz 512
#define Dsz 768
#define Tsz 12
#define Asz 64
#define N1  1536   // Tsz*Asz*2
#define Msz 8192   // Bsz*Lsz

typedef __bf16 bf16;
typedef bf16 bf16x2 __attribute__((ext_vector_type(2)));
typedef bf16 bf16x4 __attribute__((ext_vector_type(4)));
typedef bf16 bf16x8 __attribute__((ext_vector_type(8)));
typedef float f32x4 __attribute__((ext_vector_type(4)));

__device__ inline void load_lds16(const bf16* g, bf16* l) {
    __builtin_amdgcn_global_load_lds((const __attribute__((address_space(1))) void*)g,
                                     (__attribute__((address_space(3))) void*)l, 16, 0, 0);
}

// ---- prep: cos/sin tables [512][64] f32 ----
__global__ void rope_table_kernel(float* __restrict__ Tc, float* __restrict__ Ts) {
    int tid = blockIdx.x * blockDim.x + threadIdx.x;   // 512*64
    int l = tid >> 6, a = tid & 63;
    float theta = expf(-0.28782313662425575f * (float)(a >> 1));  // 10000^(-(a>>1)/32)
    float pe = (float)l * theta;
    float s, c;
    sincosf(pe, &s, &c);
    Tc[tid] = c; Ts[tid] = s;
}

// ---- prep: fp32 -> bf16 convert of input_feature [8192,768] ----
__global__ void cvt_input_kernel(const float* __restrict__ in, bf16* __restrict__ out) {
    int i = blockIdx.x * blockDim.x + threadIdx.x;   // one thread = 4 elems
    float4 v = ((const float4*)in)[i];
    bf16x4 o;
    o[0] = (bf16)v.x; o[1] = (bf16)v.y; o[2] = (bf16)v.z; o[3] = (bf16)v.w;
    ((bf16x4*)out)[i] = o;
}

// ---- prep: W [768,1536] fp32 -> Wt [1536,768] bf16 (K contiguous per row) ----
__global__ void cvt_w_kernel(const float* __restrict__ W, bf16* __restrict__ Wt) {
    int tid = blockIdx.x * blockDim.x + threadIdx.x;  // N1 * (Dsz/8) threads
    int n  = tid % N1;
    int k0 = (tid / N1) * 8;
    bf16x8 o;
#pragma unroll
    for (int j = 0; j < 8; ++j) o[j] = (bf16)W[(size_t)(k0 + j) * N1 + n];
    *(bf16x8*)(Wt + (size_t)n * Dsz + k0) = o;
}

// ---- GEMM1 + fused RoPE: computes X tile in LDS, ropes it, writes Qr/Kr ----
// 128x128 tile = 128 rows x one head t. m97 staging, 2-phase loop.
#define BK 32
#define XPAD 130   // Xs row stride in elems (pad 2 -> rope b32 reads conflict-free)
__global__ __launch_bounds__(256) void gemm1_kernel(
    const bf16* __restrict__ Abf, const bf16* __restrict__ Wt,
    const float* __restrict__ bias,
    const float* __restrict__ Tc, const float* __restrict__ Ts,
    bf16* __restrict__ Qr, bf16* __restrict__ Kr) {
    __shared__ char smem[128 * XPAD * 2];       // 33280 B; staging (32768 B) aliased on top
    bf16* AsmP = (bf16*)smem;                    // [2][128*BK]
    bf16* BsmP = (bf16*)(smem + 16384);          // [2][128*BK]
    bf16* Xs   = (bf16*)smem;                    // [128][XPAD]

    const int tid  = threadIdx.x;
    const int wave = tid >> 6, lane = tid & 63;
    const int bm = blockIdx.y * 128, bn = blockIdx.x * 128;
    const int l15 = lane & 15;
    const int klB = (lane >> 4) * 16;          // byte offset of k-slice in a 32-elem row
    const int wr = (wave >> 1) * 64;           // wave row offset in tile
    const int wc = (wave & 1) * 64;            // wave col offset in tile

    const int srow0 = tid >> 2;                 // staging rows 0..63
    const int scol  = (tid & 3) * 8;            // k offset

    f32x4 acc[4][4] = {};

#define STAGE(buf, kk)                                                              \
    do {                                                                            \
        load_lds16(Abf + (size_t)(bm + srow0) * Dsz + (kk) + scol,                  \
                   &AsmP[(buf) * 4096 + srow0 * BK + scol]);                        \
        load_lds16(Abf + (size_t)(bm + 64 + srow0) * Dsz + (kk) + scol,             \
                   &AsmP[(buf) * 4096 + (64 + srow0) * BK + scol]);                 \
        load_lds16(Wt + (size_t)(bn + srow0) * Dsz + (kk) + scol,                   \
                   &BsmP[(buf) * 4096 + srow0 * BK + scol]);                        \
        load_lds16(Wt + (size_t)(bn + 64 + srow0) * Dsz + (kk) + scol,              \
                   &BsmP[(buf) * 4096 + (64 + srow0) * BK + scol]);                 \
    } while (0)

    STAGE(0, 0);
    __syncthreads();

    int cur = 0;
    const int nsteps = Dsz / BK;   // 24
    for (int t = 0; t < nsteps; ++t) {
        if (t + 1 < nsteps) STAGE(cur ^ 1, (t + 1) * BK);

        bf16x8 af[4], bfr[4];
#pragma unroll
        for (int m = 0; m < 4; ++m)
            af[m] = *(const bf16x8*)((const char*)(AsmP + cur * 4096) + (wr + m * 16 + l15) * (BK * 2) + klB);
#pragma unroll
        for (int n = 0; n < 4; ++n)
            bfr[n] = *(const bf16x8*)((const char*)(BsmP + cur * 4096) + (wc + n * 16 + l15) * (BK * 2) + klB);

#pragma unroll
        for (int m = 0; m < 4; ++m)
#pragma unroll
            for (int n = 0; n < 4; ++n)
                acc[m][n] = __builtin_amdgcn_mfma_f32_16x16x32_bf16(af[m], bfr[n], acc[m][n], 0, 0, 0);

        __syncthreads();
        cur ^= 1;
    }
#undef STAGE

    // ---- epilogue 1: acc (+bias) -> Xs (bf16) ----
    // C/D layout: col=lane&15, row=(lane>>4)*4+r
    const int row0 = wr + (lane >> 4) * 4;
#pragma unroll
    for (int n = 0; n < 4; ++n) {
        const int col = wc + n * 16 + l15;
        const float bv = bias[bn + col];
#pragma unroll
        for (int m = 0; m < 4; ++m) {
#pragma unroll
            for (int r = 0; r < 4; ++r) {
                Xs[(row0 + m * 16 + r) * XPAD + col] = (bf16)(acc[m][n][r] + bv);
            }
        }
    }
    __syncthreads();

    // ---- epilogue 2: RoPE + split on the LDS tile ----
    // thread = (row r, half h); a = h*32 + ai, ai in [0,32)
    {
        const int r = tid >> 1, h = tid & 1;
        const int grow = bm + r;                  // global row = b*512 + l
        const int b = grow >> 9, l = grow & 511;
        const int t_head = blockIdx.x;            // 128 cols == one head
        const bf16* xrow = Xs + r * XPAD;
        const float sgn = h ? 1.f : -1.f;
        const float* tcp = Tc + (l * 64 + h * 32);
        const float* tsp = Ts + (l * 64 + h * 32);
        bf16* qo = Qr + (((size_t)(b * Tsz + t_head) * Lsz) + l) * Asz + h * 32;
        bf16* ko = Kr + (((size_t)(b * Tsz + t_head) * Lsz) + l) * Asz + h * 32;

#pragma unroll
        for (int c8 = 0; c8 < 4; ++c8) {
            bf16x8 qv, kv;
#pragma unroll
            for (int j = 0; j < 8; ++j) {
                const int ai = c8 * 8 + j;
                const int a  = h * 32 + ai;
                const int a2 = h ? (2 * ai) : (2 * a + 1);
                bf16x2 sp = *(const bf16x2*)(xrow + 2 * a);
                bf16x2 pp = *(const bf16x2*)(xrow + 2 * a2);
                const float c = tcp[ai], s = tsp[ai];
                const float q  = (float)sp[0], k  = (float)sp[1];
                const float q2 = (float)pp[0], k2 = (float)pp[1];
                qv[j] = (bf16)(q * c + sgn * q2 * s);
                kv[j] = (bf16)(k * c + sgn * k2 * s);
            }
            *(bf16x8*)(qo + c8 * 8) = qv;
            *(bf16x8*)(ko + c8 * 8) = kv;
        }
    }
}

// ---- QK^T + mask: out[b,t,i,j]; 64x64 tile per block ----
__global__ __launch_bounds__(256) void qk_kernel(
    const bf16* __restrict__ Qr, const bf16* __restrict__ Kr,
    const int* __restrict__ mask, float* __restrict__ out) {
    int z = blockIdx.z;               // b*T + t
    int b = z / Tsz;
    int i0 = blockIdx.y * 64, j0 = blockIdx.x * 64;
    float* ob = out + (size_t)z * Lsz * Lsz;

    if (blockIdx.y > blockIdx.x) {
        // fully below diagonal: pure -1e12 fill
        int r  = threadIdx.x >> 2;
        int cs = threadIdx.x & 3;
        float4 f; f.x = f.y = f.z = f.w = -1e12f;
        float4* p = (float4*)(ob + (size_t)(i0 + r) * Lsz + j0 + cs * 16);
        p[0] = f; p[1] = f; p[2] = f; p[3] = f;
        return;
    }

    int wave = threadIdx.x >> 6, lane = threadIdx.x & 63;
    int l15 = lane & 15;
    int kl  = (lane >> 4) * 8;
    const bf16* Qb = Qr + (size_t)z * Lsz * Asz;
    const bf16* Kb = Kr + (size_t)z * Lsz * Asz;

    int qrow = i0 + wave * 16 + l15;
    bf16x8 a0 = *(const bf16x8*)(Qb + (size_t)qrow * 64 + kl);
    bf16x8 a1 = *(const bf16x8*)(Qb + (size_t)qrow * 64 + 32 + kl);

    f32x4 acc[4] = {};
#pragma unroll
    for (int ct = 0; ct < 4; ++ct) {
        int krow = j0 + ct * 16 + l15;
        bf16x8 b0 = *(const bf16x8*)(Kb + (size_t)krow * 64 + kl);
        bf16x8 b1 = *(const bf16x8*)(Kb + (size_t)krow * 64 + 32 + kl);
        acc[ct] = __builtin_amdgcn_mfma_f32_16x16x32_bf16(a0, b0, acc[ct], 0, 0, 0);
        acc[ct] = __builtin_amdgcn_mfma_f32_16x16x32_bf16(a1, b1, acc[ct], 0, 0, 0);
    }

    const int* mb = mask + b * Lsz;
    int row0 = i0 + wave * 16 + (lane >> 4) * 4;
#pragma unroll
    for (int ct = 0; ct < 4; ++ct) {
        int col = j0 + ct * 16 + l15;
        bool mj = mb[col] > 0;
#pragma unroll
        for (int r = 0; r < 4; ++r) {
            int row = row0 + r;
            bool keep = mj && (mb[row] > 0) && (row <= col);
            ob[(size_t)row * Lsz + col] = keep ? acc[ct][r] : -1e12f;
        }
    }
}

extern "C" void kernel_launch(void* const* d_in, const int* in_sizes, int n_in,
                              void* d_out, int out_size, void* d_ws, size_t ws_size,
                              hipStream_t stream) {
    const float* in_f  = (const float*)d_in[0];
    const int*   amask = (const int*)d_in[1];
    const float* W     = (const float*)d_in[2];
    const float* bias  = (const float*)d_in[3];
    float* out = (float*)d_out;

    char* ws = (char*)d_ws;
    bf16*  Abf = (bf16*)ws;                                  // 8192*768*2   = 12,582,912 B
    bf16*  Wt  = (bf16*)(ws + 12582912);                     // 1536*768*2   =  2,359,296 B
    bf16*  Qr  = (bf16*)(ws + 14942208);                     // 192*512*64*2 = 12,582,912 B
    bf16*  Kr  = (bf16*)(ws + 27525120);                     // same
    float* Tc  = (float*)(ws + 40108032);                    // 512*64*4     =    131,072 B
    float* Ts  = (float*)(ws + 40239104);                    // same

    // prep
    rope_table_kernel<<<(Lsz * Asz) / 256, 256, 0, stream>>>(Tc, Ts);
    cvt_input_kernel<<<(Msz * Dsz / 4) / 256, 256, 0, stream>>>(in_f, Abf);
    cvt_w_kernel<<<(N1 * (Dsz / 8)) / 256, 256, 0, stream>>>(W, Wt);
    // projection GEMM + fused RoPE (128x128 tiles; col tile == head)
    gemm1_kernel<<<dim3(N1 / 128, Msz / 128), 256, 0, stream>>>(Abf, Wt, bias, Tc, Ts, Qr, Kr);
    // scores + mask
    qk_kernel<<<dim3(Lsz / 64, Lsz / 64, Bsz * Tsz), 256, 0, stream>>>(Qr, Kr, amask, out);
}

// Round 4
// 118.281 us; speedup vs baseline: 2.3135x; 1.1813x over previous
//
#include <hip/hip_runtime.h>
#include <hip/hip_bf16.h>

// Problem constants
#define Bsz 16
#define Lsz 512
#define Dsz 768
#define Tsz 12
#define Asz 64
#define N1  1536   // Tsz*Asz*2
#define Msz 8192   // Bsz*Lsz

typedef __bf16 bf16;
typedef bf16 bf16x2 __attribute__((ext_vector_type(2)));
typedef bf16 bf16x4 __attribute__((ext_vector_type(4)));
typedef bf16 bf16x8 __attribute__((ext_vector_type(8)));
typedef float f32x4 __attribute__((ext_vector_type(4)));
typedef unsigned long long u64;

__device__ inline void load_lds16(const bf16* g, bf16* l) {
    __builtin_amdgcn_global_load_lds((const __attribute__((address_space(1))) void*)g,
                                     (__attribute__((address_space(3))) void*)l, 16, 0, 0);
}

// ---- fused prep: cvt_input | cvt_w | rope tables | mask bitfields ----
// blocks [0,6144): input f32->bf16 ; [6144,6720): W transpose+cvt ;
// [6720,6848): cos/sin tables ; [6848,6880): mask ballot bits
__global__ __launch_bounds__(256) void prep_kernel(
    const float* __restrict__ in, const float* __restrict__ W,
    const int* __restrict__ mask,
    bf16* __restrict__ Abf, bf16* __restrict__ Wt,
    float* __restrict__ Tc, float* __restrict__ Ts, u64* __restrict__ Mbits) {
    int blk = blockIdx.x;
    if (blk < 6144) {                       // cvt_input: 8192*768/4 threads
        int i = blk * 256 + threadIdx.x;
        float4 v = ((const float4*)in)[i];
        bf16x4 o;
        o[0] = (bf16)v.x; o[1] = (bf16)v.y; o[2] = (bf16)v.z; o[3] = (bf16)v.w;
        ((bf16x4*)Abf)[i] = o;
    } else if (blk < 6720) {                // cvt_w: N1*(Dsz/8) threads
        int tid = (blk - 6144) * 256 + threadIdx.x;
        int n  = tid % N1;
        int k0 = (tid / N1) * 8;
        bf16x8 o;
#pragma unroll
        for (int j = 0; j < 8; ++j) o[j] = (bf16)W[(size_t)(k0 + j) * N1 + n];
        *(bf16x8*)(Wt + (size_t)n * Dsz + k0) = o;
    } else if (blk < 6848) {                // rope tables: 512*64 threads
        int tid = (blk - 6720) * 256 + threadIdx.x;
        int l = tid >> 6, a = tid & 63;
        float theta = expf(-0.28782313662425575f * (float)(a >> 1));  // 10000^(-(a>>1)/32)
        float pe = (float)l * theta;
        float s, c;
        sincosf(pe, &s, &c);
        Tc[tid] = c; Ts[tid] = s;
    } else {                                // mask bits: 16*512 threads
        int tid = (blk - 6848) * 256 + threadIdx.x;
        u64 bal = __ballot(mask[tid] > 0);
        if ((tid & 63) == 0) Mbits[tid >> 6] = bal;
    }
}

// ---- GEMM1 + fused RoPE: X tile in LDS -> rope -> Qr/Kr ----
// 128x128 tile = 128 rows x one head. m97 staging, 2-phase loop, XCD swizzle.
#define BK 32
#define XPAD 130
__global__ __launch_bounds__(256) void gemm1_kernel(
    const bf16* __restrict__ Abf, const bf16* __restrict__ Wt,
    const float* __restrict__ bias,
    const float* __restrict__ Tc, const float* __restrict__ Ts,
    bf16* __restrict__ Qr, bf16* __restrict__ Kr) {
    __shared__ char smem[128 * XPAD * 2];       // 33280 B; staging (32768 B) aliased
    bf16* AsmP = (bf16*)smem;                    // [2][128*BK]
    bf16* BsmP = (bf16*)(smem + 16384);          // [2][128*BK]
    bf16* Xs   = (bf16*)smem;                    // [128][XPAD]

    // XCD-aware swizzle: 768 blocks, 768%8==0 -> 96 contiguous tiles per XCD
    const int flat = blockIdx.y * gridDim.x + blockIdx.x;   // dispatch order (x fastest)
    const int tile = (flat & 7) * 96 + (flat >> 3);
    const int bx = tile % 12, by = tile / 12;

    const int tid  = threadIdx.x;
    const int wave = tid >> 6, lane = tid & 63;
    const int bm = by * 128, bn = bx * 128;
    const int l15 = lane & 15;
    const int klB = (lane >> 4) * 16;
    const int wr = (wave >> 1) * 64;
    const int wc = (wave & 1) * 64;

    const int srow0 = tid >> 2;
    const int scol  = (tid & 3) * 8;

    f32x4 acc[4][4] = {};

#define STAGE(buf, kk)                                                              \
    do {                                                                            \
        load_lds16(Abf + (size_t)(bm + srow0) * Dsz + (kk) + scol,                  \
                   &AsmP[(buf) * 4096 + srow0 * BK + scol]);                        \
        load_lds16(Abf + (size_t)(bm + 64 + srow0) * Dsz + (kk) + scol,             \
                   &AsmP[(buf) * 4096 + (64 + srow0) * BK + scol]);                 \
        load_lds16(Wt + (size_t)(bn + srow0) * Dsz + (kk) + scol,                   \
                   &BsmP[(buf) * 4096 + srow0 * BK + scol]);                        \
        load_lds16(Wt + (size_t)(bn + 64 + srow0) * Dsz + (kk) + scol,              \
                   &BsmP[(buf) * 4096 + (64 + srow0) * BK + scol]);                 \
    } while (0)

    STAGE(0, 0);
    __syncthreads();

    int cur = 0;
    const int nsteps = Dsz / BK;   // 24
    for (int t = 0; t < nsteps; ++t) {
        if (t + 1 < nsteps) STAGE(cur ^ 1, (t + 1) * BK);

        bf16x8 af[4], bfr[4];
#pragma unroll
        for (int m = 0; m < 4; ++m)
            af[m] = *(const bf16x8*)((const char*)(AsmP + cur * 4096) + (wr + m * 16 + l15) * (BK * 2) + klB);
#pragma unroll
        for (int n = 0; n < 4; ++n)
            bfr[n] = *(const bf16x8*)((const char*)(BsmP + cur * 4096) + (wc + n * 16 + l15) * (BK * 2) + klB);

#pragma unroll
        for (int m = 0; m < 4; ++m)
#pragma unroll
            for (int n = 0; n < 4; ++n)
                acc[m][n] = __builtin_amdgcn_mfma_f32_16x16x32_bf16(af[m], bfr[n], acc[m][n], 0, 0, 0);

        __syncthreads();
        cur ^= 1;
    }
#undef STAGE

    // epilogue 1: acc (+bias) -> Xs (bf16). C/D: col=lane&15, row=(lane>>4)*4+r
    const int row0 = wr + (lane >> 4) * 4;
#pragma unroll
    for (int n = 0; n < 4; ++n) {
        const int col = wc + n * 16 + l15;
        const float bv = bias[bn + col];
#pragma unroll
        for (int m = 0; m < 4; ++m) {
#pragma unroll
            for (int r = 0; r < 4; ++r) {
                Xs[(row0 + m * 16 + r) * XPAD + col] = (bf16)(acc[m][n][r] + bv);
            }
        }
    }
    __syncthreads();

    // epilogue 2: RoPE + split (thread = row r, half h)
    {
        const int r = tid >> 1, h = tid & 1;
        const int grow = bm + r;                  // b*512 + l
        const int b = grow >> 9, l = grow & 511;
        const int t_head = bx;
        const bf16* xrow = Xs + r * XPAD;
        const float sgn = h ? 1.f : -1.f;
        const float* tcp = Tc + (l * 64 + h * 32);
        const float* tsp = Ts + (l * 64 + h * 32);
        bf16* qo = Qr + (((size_t)(b * Tsz + t_head) * Lsz) + l) * Asz + h * 32;
        bf16* ko = Kr + (((size_t)(b * Tsz + t_head) * Lsz) + l) * Asz + h * 32;

#pragma unroll
        for (int c8 = 0; c8 < 4; ++c8) {
            bf16x8 qv, kv;
#pragma unroll
            for (int j = 0; j < 8; ++j) {
                const int ai = c8 * 8 + j;
                const int a  = h * 32 + ai;
                const int a2 = h ? (2 * ai) : (2 * a + 1);
                bf16x2 sp = *(const bf16x2*)(xrow + 2 * a);
                bf16x2 pp = *(const bf16x2*)(xrow + 2 * a2);
                const float c = tcp[ai], s = tsp[ai];
                const float q  = (float)sp[0], k  = (float)sp[1];
                const float q2 = (float)pp[0], k2 = (float)pp[1];
                qv[j] = (bf16)(q * c + sgn * q2 * s);
                kv[j] = (bf16)(k * c + sgn * k2 * s);
            }
            *(bf16x8*)(qo + c8 * 8) = qv;
            *(bf16x8*)(ko + c8 * 8) = kv;
        }
    }
}

// ---- QK^T + mask. Swapped operands (A=K,B=Q): lane holds 4 consecutive j
// -> float4 stores. Mask via bitfields, triu via j>=i. 64x64 tile/block.
__global__ __launch_bounds__(256) void qk_kernel(
    const bf16* __restrict__ Qr, const bf16* __restrict__ Kr,
    const u64* __restrict__ Mbits, float* __restrict__ out) {
    const int z = blockIdx.z;               // b*T + t
    const int b = z / Tsz;
    const int i0 = blockIdx.y * 64, j0 = blockIdx.x * 64;
    float* ob = out + (size_t)z * Lsz * Lsz;

    if (blockIdx.y > blockIdx.x) {          // below diagonal: -1e12 fill
        int r  = threadIdx.x >> 2;
        int cs = threadIdx.x & 3;
        float4 f; f.x = f.y = f.z = f.w = -1e12f;
        float4* p = (float4*)(ob + (size_t)(i0 + r) * Lsz + j0 + cs * 16);
        p[0] = f; p[1] = f; p[2] = f; p[3] = f;
        return;
    }

    const int wave = threadIdx.x >> 6, lane = threadIdx.x & 63;
    const int l15 = lane & 15, hi = lane >> 4;
    const bf16* Qb = Qr + (size_t)z * Lsz * Asz;
    const bf16* Kb = Kr + (size_t)z * Lsz * Asz;

    // B operand: 16 Q-rows per wave (i); A operand: 64 K-rows via ct (j)
    const int irow = i0 + wave * 16 + l15;
    const bf16x8 q0 = *(const bf16x8*)(Qb + (size_t)irow * 64 + hi * 8);
    const bf16x8 q1 = *(const bf16x8*)(Qb + (size_t)irow * 64 + 32 + hi * 8);

    f32x4 acc[4] = {};
#pragma unroll
    for (int ct = 0; ct < 4; ++ct) {
        const int jrow = j0 + ct * 16 + l15;
        bf16x8 k0 = *(const bf16x8*)(Kb + (size_t)jrow * 64 + hi * 8);
        bf16x8 k1 = *(const bf16x8*)(Kb + (size_t)jrow * 64 + 32 + hi * 8);
        acc[ct] = __builtin_amdgcn_mfma_f32_16x16x32_bf16(k0, q0, acc[ct], 0, 0, 0);
        acc[ct] = __builtin_amdgcn_mfma_f32_16x16x32_bf16(k1, q1, acc[ct], 0, 0, 0);
    }

    // masks: block-uniform u64 bitfields (s_load), per-lane bit tests
    const u64 jb = Mbits[b * 8 + (j0 >> 6)];
    const u64 ib = Mbits[b * 8 + (i0 >> 6)];
    const bool mi = (ib >> (wave * 16 + l15)) & 1;

#pragma unroll
    for (int ct = 0; ct < 4; ++ct) {
        const int jbase = ct * 16 + hi * 4;
        float4 v;
#pragma unroll
        for (int r = 0; r < 4; ++r) {
            const int j = j0 + jbase + r;
            const bool keep = mi && ((jb >> (jbase + r)) & 1) && (irow <= j);
            v[r] = keep ? acc[ct][r] : -1e12f;
        }
        *(float4*)(ob + (size_t)irow * Lsz + j0 + jbase) = v;
    }
}

extern "C" void kernel_launch(void* const* d_in, const int* in_sizes, int n_in,
                              void* d_out, int out_size, void* d_ws, size_t ws_size,
                              hipStream_t stream) {
    const float* in_f  = (const float*)d_in[0];
    const int*   amask = (const int*)d_in[1];
    const float* W     = (const float*)d_in[2];
    const float* bias  = (const float*)d_in[3];
    float* out = (float*)d_out;

    char* ws = (char*)d_ws;
    bf16*  Abf   = (bf16*)ws;                                // 12,582,912 B
    bf16*  Wt    = (bf16*)(ws + 12582912);                   //  2,359,296 B
    bf16*  Qr    = (bf16*)(ws + 14942208);                   // 12,582,912 B
    bf16*  Kr    = (bf16*)(ws + 27525120);                   // 12,582,912 B
    float* Tc    = (float*)(ws + 40108032);                  //    131,072 B
    float* Ts    = (float*)(ws + 40239104);                  //    131,072 B
    u64*   Mbits = (u64*)(ws + 40370176);                    //      1,024 B

    prep_kernel<<<6880, 256, 0, stream>>>(in_f, W, amask, Abf, Wt, Tc, Ts, Mbits);
    gemm1_kernel<<<dim3(N1 / 128, Msz / 128), 256, 0, stream>>>(Abf, Wt, bias, Tc, Ts, Qr, Kr);
    qk_kernel<<<dim3(Lsz / 64, Lsz / 64, Bsz * Tsz), 256, 0, stream>>>(Qr, Kr, Mbits, out);
}

// Round 5
// 117.290 us; speedup vs baseline: 2.3330x; 1.0084x over previous
//
#include <hip/hip_runtime.h>
#include <hip/hip_bf16.h>

// Problem constants
#define Bsz 16
#define Lsz 512
#define Dsz 768
#define Tsz 12
#define Asz 64
#define N1  1536   // Tsz*Asz*2
#define Msz 8192   // Bsz*Lsz

typedef __bf16 bf16;
typedef bf16 bf16x2 __attribute__((ext_vector_type(2)));
typedef bf16 bf16x4 __attribute__((ext_vector_type(4)));
typedef bf16 bf16x8 __attribute__((ext_vector_type(8)));
typedef float f32x4 __attribute__((ext_vector_type(4)));
typedef unsigned long long u64;

__device__ inline void load_lds16(const bf16* g, bf16* l) {
    __builtin_amdgcn_global_load_lds((const __attribute__((address_space(1))) void*)g,
                                     (__attribute__((address_space(3))) void*)l, 16, 0, 0);
}

// ---- fused prep: cvt_input | cvt_w | rope tables | mask bitfields ----
__global__ __launch_bounds__(256) void prep_kernel(
    const float* __restrict__ in, const float* __restrict__ W,
    const int* __restrict__ mask,
    bf16* __restrict__ Abf, bf16* __restrict__ Wt,
    float* __restrict__ Tc, float* __restrict__ Ts, u64* __restrict__ Mbits) {
    int blk = blockIdx.x;
    if (blk < 6144) {                       // cvt_input: 8192*768/4 threads
        int i = blk * 256 + threadIdx.x;
        float4 v = ((const float4*)in)[i];
        bf16x4 o;
        o[0] = (bf16)v.x; o[1] = (bf16)v.y; o[2] = (bf16)v.z; o[3] = (bf16)v.w;
        ((bf16x4*)Abf)[i] = o;
    } else if (blk < 6720) {                // cvt_w: N1*(Dsz/8) threads
        int tid = (blk - 6144) * 256 + threadIdx.x;
        int n  = tid % N1;
        int k0 = (tid / N1) * 8;
        bf16x8 o;
#pragma unroll
        for (int j = 0; j < 8; ++j) o[j] = (bf16)W[(size_t)(k0 + j) * N1 + n];
        *(bf16x8*)(Wt + (size_t)n * Dsz + k0) = o;
    } else if (blk < 6848) {                // rope tables: 512*64 threads
        int tid = (blk - 6720) * 256 + threadIdx.x;
        int l = tid >> 6, a = tid & 63;
        float theta = expf(-0.28782313662425575f * (float)(a >> 1));  // 10000^(-(a>>1)/32)
        float pe = (float)l * theta;
        float s, c;
        sincosf(pe, &s, &c);
        Tc[tid] = c; Ts[tid] = s;
    } else {                                // mask bits: 16*512 threads
        int tid = (blk - 6848) * 256 + threadIdx.x;
        u64 bal = __ballot(mask[tid] > 0);
        if ((tid & 63) == 0) Mbits[tid >> 6] = bal;
    }
}

// ---- GEMM1 + fused RoPE ----
// 128x128 tile, 4 waves, 16x16x32 MFMA. Triple-buffered LDS, counted
// vmcnt(4) + raw s_barrier: stage t+2 while computing t; loads stay in
// flight across barriers (never vmcnt(0) in the loop).
#define BK 32
#define XPAD 130
#define BUFB 16384   // bytes per buffer (A 8192 + B 8192)
__global__ __launch_bounds__(256) void gemm1_kernel(
    const bf16* __restrict__ Abf, const bf16* __restrict__ Wt,
    const float* __restrict__ bias,
    const float* __restrict__ Tc, const float* __restrict__ Ts,
    bf16* __restrict__ Qr, bf16* __restrict__ Kr) {
    __shared__ char smem[3 * BUFB];              // 49152 B; Xs (33280 B) aliased
    bf16* Xs = (bf16*)smem;                      // [128][XPAD] epilogue tile

    // XCD-aware swizzle: 768 blocks, 768%8==0 -> 96 contiguous tiles per XCD
    const int flat = blockIdx.y * gridDim.x + blockIdx.x;
    const int tile = (flat & 7) * 96 + (flat >> 3);
    const int bx = tile % 12, by = tile / 12;

    const int tid  = threadIdx.x;
    const int wave = tid >> 6, lane = tid & 63;
    const int bm = by * 128, bn = bx * 128;
    const int l15 = lane & 15;
    const int klB = (lane >> 4) * 16;
    const int wr = (wave >> 1) * 64;
    const int wc = (wave & 1) * 64;

    const int srow0 = tid >> 2;                 // staging rows 0..63
    const int scol  = (tid & 3) * 8;            // k offset

    f32x4 acc[4][4] = {};

    // buf layout: A at smem+buf*BUFB, B at +8192
#define STAGE(buf, kk)                                                              \
    do {                                                                            \
        bf16* Ab = (bf16*)(smem + (buf) * BUFB);                                    \
        bf16* Bb = (bf16*)(smem + (buf) * BUFB + 8192);                             \
        load_lds16(Abf + (size_t)(bm + srow0) * Dsz + (kk) + scol,                  \
                   &Ab[srow0 * BK + scol]);                                         \
        load_lds16(Abf + (size_t)(bm + 64 + srow0) * Dsz + (kk) + scol,             \
                   &Ab[(64 + srow0) * BK + scol]);                                  \
        load_lds16(Wt + (size_t)(bn + srow0) * Dsz + (kk) + scol,                   \
                   &Bb[srow0 * BK + scol]);                                         \
        load_lds16(Wt + (size_t)(bn + 64 + srow0) * Dsz + (kk) + scol,              \
                   &Bb[(64 + srow0) * BK + scol]);                                  \
    } while (0)

    const int nsteps = Dsz / BK;   // 24
    STAGE(0, 0);
    STAGE(1, BK);
    asm volatile("s_waitcnt vmcnt(4)" ::: "memory");   // buf0 landed (buf1 in flight)
    __builtin_amdgcn_s_barrier();

    int cur = 0;
    for (int t = 0; t < nsteps; ++t) {
        int stg = cur + 2; if (stg >= 3) stg -= 3;
        if (t + 2 < nsteps) STAGE(stg, (t + 2) * BK);

        const char* Abase = smem + cur * BUFB;
        const char* Bbase = smem + cur * BUFB + 8192;
        bf16x8 af[4], bfr[4];
#pragma unroll
        for (int m = 0; m < 4; ++m)
            af[m] = *(const bf16x8*)(Abase + (wr + m * 16 + l15) * (BK * 2) + klB);
#pragma unroll
        for (int n = 0; n < 4; ++n)
            bfr[n] = *(const bf16x8*)(Bbase + (wc + n * 16 + l15) * (BK * 2) + klB);

#pragma unroll
        for (int m = 0; m < 4; ++m)
#pragma unroll
            for (int n = 0; n < 4; ++n)
                acc[m][n] = __builtin_amdgcn_mfma_f32_16x16x32_bf16(af[m], bfr[n], acc[m][n], 0, 0, 0);

        if (t + 1 < nsteps) {
            if (t + 2 < nsteps) asm volatile("s_waitcnt vmcnt(4)" ::: "memory");
            else                asm volatile("s_waitcnt vmcnt(0)" ::: "memory");
            __builtin_amdgcn_s_barrier();
        }
        cur = cur + 1; if (cur >= 3) cur -= 3;
    }
#undef STAGE

    __syncthreads();   // all waves done reading bufs; smem becomes Xs

    // epilogue 1: acc (+bias) -> Xs (bf16). C/D: col=lane&15, row=(lane>>4)*4+r
    const int row0 = wr + (lane >> 4) * 4;
#pragma unroll
    for (int n = 0; n < 4; ++n) {
        const int col = wc + n * 16 + l15;
        const float bv = bias[bn + col];
#pragma unroll
        for (int m = 0; m < 4; ++m) {
#pragma unroll
            for (int r = 0; r < 4; ++r) {
                Xs[(row0 + m * 16 + r) * XPAD + col] = (bf16)(acc[m][n][r] + bv);
            }
        }
    }
    __syncthreads();

    // epilogue 2: RoPE + split (thread = row r, half h)
    {
        const int r = tid >> 1, h = tid & 1;
        const int grow = bm + r;                  // b*512 + l
        const int b = grow >> 9, l = grow & 511;
        const int t_head = bx;
        const bf16* xrow = Xs + r * XPAD;
        const float sgn = h ? 1.f : -1.f;
        const float* tcp = Tc + (l * 64 + h * 32);
        const float* tsp = Ts + (l * 64 + h * 32);
        bf16* qo = Qr + (((size_t)(b * Tsz + t_head) * Lsz) + l) * Asz + h * 32;
        bf16* ko = Kr + (((size_t)(b * Tsz + t_head) * Lsz) + l) * Asz + h * 32;

#pragma unroll
        for (int c8 = 0; c8 < 4; ++c8) {
            bf16x8 qv, kv;
#pragma unroll
            for (int j = 0; j < 8; ++j) {
                const int ai = c8 * 8 + j;
                const int a  = h * 32 + ai;
                const int a2 = h ? (2 * ai) : (2 * a + 1);
                bf16x2 sp = *(const bf16x2*)(xrow + 2 * a);
                bf16x2 pp = *(const bf16x2*)(xrow + 2 * a2);
                const float c = tcp[ai], s = tsp[ai];
                const float q  = (float)sp[0], k  = (float)sp[1];
                const float q2 = (float)pp[0], k2 = (float)pp[1];
                qv[j] = (bf16)(q * c + sgn * q2 * s);
                kv[j] = (bf16)(k * c + sgn * k2 * s);
            }
            *(bf16x8*)(qo + c8 * 8) = qv;
            *(bf16x8*)(ko + c8 * 8) = kv;
        }
    }
}

// ---- QK^T + mask. Swapped operands (A=K,B=Q): lane holds 4 consecutive j
// -> float4 stores. Mask via bitfields, triu via j>=i. 64x64 tile/block.
__global__ __launch_bounds__(256) void qk_kernel(
    const bf16* __restrict__ Qr, const bf16* __restrict__ Kr,
    const u64* __restrict__ Mbits, float* __restrict__ out) {
    const int z = blockIdx.z;               // b*T + t
    const int b = z / Tsz;
    const int i0 = blockIdx.y * 64, j0 = blockIdx.x * 64;
    float* ob = out + (size_t)z * Lsz * Lsz;

    if (blockIdx.y > blockIdx.x) {          // below diagonal: -1e12 fill
        int r  = threadIdx.x >> 2;
        int cs = threadIdx.x & 3;
        float4 f; f.x = f.y = f.z = f.w = -1e12f;
        float4* p = (float4*)(ob + (size_t)(i0 + r) * Lsz + j0 + cs * 16);
        p[0] = f; p[1] = f; p[2] = f; p[3] = f;
        return;
    }

    const int wave = threadIdx.x >> 6, lane = threadIdx.x & 63;
    const int l15 = lane & 15, hi = lane >> 4;
    const bf16* Qb = Qr + (size_t)z * Lsz * Asz;
    const bf16* Kb = Kr + (size_t)z * Lsz * Asz;

    const int irow = i0 + wave * 16 + l15;
    const bf16x8 q0 = *(const bf16x8*)(Qb + (size_t)irow * 64 + hi * 8);
    const bf16x8 q1 = *(const bf16x8*)(Qb + (size_t)irow * 64 + 32 + hi * 8);

    f32x4 acc[4] = {};
#pragma unroll
    for (int ct = 0; ct < 4; ++ct) {
        const int jrow = j0 + ct * 16 + l15;
        bf16x8 k0 = *(const bf16x8*)(Kb + (size_t)jrow * 64 + hi * 8);
        bf16x8 k1 = *(const bf16x8*)(Kb + (size_t)jrow * 64 + 32 + hi * 8);
        acc[ct] = __builtin_amdgcn_mfma_f32_16x16x32_bf16(k0, q0, acc[ct], 0, 0, 0);
        acc[ct] = __builtin_amdgcn_mfma_f32_16x16x32_bf16(k1, q1, acc[ct], 0, 0, 0);
    }

    const u64 jb = Mbits[b * 8 + (j0 >> 6)];
    const u64 ib = Mbits[b * 8 + (i0 >> 6)];
    const bool mi = (ib >> (wave * 16 + l15)) & 1;

#pragma unroll
    for (int ct = 0; ct < 4; ++ct) {
        const int jbase = ct * 16 + hi * 4;
        float4 v;
#pragma unroll
        for (int r = 0; r < 4; ++r) {
            const int j = j0 + jbase + r;
            const bool keep = mi && ((jb >> (jbase + r)) & 1) && (irow <= j);
            v[r] = keep ? acc[ct][r] : -1e12f;
        }
        *(float4*)(ob + (size_t)irow * Lsz + j0 + jbase) = v;
    }
}

extern "C" void kernel_launch(void* const* d_in, const int* in_sizes, int n_in,
                              void* d_out, int out_size, void* d_ws, size_t ws_size,
                              hipStream_t stream) {
    const float* in_f  = (const float*)d_in[0];
    const int*   amask = (const int*)d_in[1];
    const float* W     = (const float*)d_in[2];
    const float* bias  = (const float*)d_in[3];
    float* out = (float*)d_out;

    char* ws = (char*)d_ws;
    bf16*  Abf   = (bf16*)ws;                                // 12,582,912 B
    bf16*  Wt    = (bf16*)(ws + 12582912);                   //  2,359,296 B
    bf16*  Qr    = (bf16*)(ws + 14942208);                   // 12,582,912 B
    bf16*  Kr    = (bf16*)(ws + 27525120);                   // 12,582,912 B
    float* Tc    = (float*)(ws + 40108032);                  //    131,072 B
    float* Ts    = (float*)(ws + 40239104);                  //    131,072 B
    u64*   Mbits = (u64*)(ws + 40370176);                    //      1,024 B

    prep_kernel<<<6880, 256, 0, stream>>>(in_f, W, amask, Abf, Wt, Tc, Ts, Mbits);
    gemm1_kernel<<<dim3(N1 / 128, Msz / 128), 256, 0, stream>>>(Abf, Wt, bias, Tc, Ts, Qr, Kr);
    qk_kernel<<<dim3(Lsz / 64, Lsz / 64, Bsz * Tsz), 256, 0, stream>>>(Qr, Kr, Mbits, out);
}

// Round 6
// 99.307 us; speedup vs baseline: 2.7555x; 1.1811x over previous
//
#include <hip/hip_runtime.h>
#include <hip/hip_bf16.h>

// Problem constants
#define Bsz 16
#define Lsz 512
#define Dsz 768
#define Tsz 12
#define Asz 64
#define N1  1536   // Tsz*Asz*2
#define Msz 8192   // Bsz*Lsz

typedef __bf16 bf16;
typedef bf16 bf16x2 __attribute__((ext_vector_type(2)));
typedef bf16 bf16x4 __attribute__((ext_vector_type(4)));
typedef bf16 bf16x8 __attribute__((ext_vector_type(8)));
typedef float f32x4 __attribute__((ext_vector_type(4)));
typedef unsigned long long u64;

__device__ inline void load_lds16(const bf16* g, bf16* l) {
    __builtin_amdgcn_global_load_lds((const __attribute__((address_space(1))) void*)g,
                                     (__attribute__((address_space(3))) void*)l, 16, 0, 0);
}

// ---- fused prep: cvt_input | cvt_w | rope tables | mask bitfields ----
__global__ __launch_bounds__(256) void prep_kernel(
    const float* __restrict__ in, const float* __restrict__ W,
    const int* __restrict__ mask,
    bf16* __restrict__ Abf, bf16* __restrict__ Wt,
    float* __restrict__ Tc, float* __restrict__ Ts, u64* __restrict__ Mbits) {
    int blk = blockIdx.x;
    if (blk < 6144) {                       // cvt_input: 8192*768/4 threads
        int i = blk * 256 + threadIdx.x;
        float4 v = ((const float4*)in)[i];
        bf16x4 o;
        o[0] = (bf16)v.x; o[1] = (bf16)v.y; o[2] = (bf16)v.z; o[3] = (bf16)v.w;
        ((bf16x4*)Abf)[i] = o;
    } else if (blk < 6720) {                // cvt_w: N1*(Dsz/8) threads
        int tid = (blk - 6144) * 256 + threadIdx.x;
        int n  = tid % N1;
        int k0 = (tid / N1) * 8;
        bf16x8 o;
#pragma unroll
        for (int j = 0; j < 8; ++j) o[j] = (bf16)W[(size_t)(k0 + j) * N1 + n];
        *(bf16x8*)(Wt + (size_t)n * Dsz + k0) = o;
    } else if (blk < 6848) {                // rope tables: 512*64 threads
        int tid = (blk - 6720) * 256 + threadIdx.x;
        int l = tid >> 6, a = tid & 63;
        float theta = expf(-0.28782313662425575f * (float)(a >> 1));  // 10000^(-(a>>1)/32)
        float pe = (float)l * theta;
        float s, c;
        sincosf(pe, &s, &c);
        Tc[tid] = c; Ts[tid] = s;
    } else {                                // mask bits: 16*512 threads
        int tid = (blk - 6848) * 256 + threadIdx.x;
        u64 bal = __ballot(mask[tid] > 0);
        if ((tid & 63) == 0) Mbits[tid >> 6] = bal;
    }
}

// ---- FUSED: per-(b,head) block: projection GEMM -> rope -> QK^T + mask ----
// 512 threads (8 waves). LDS: staging 3x40960 aliased under Xq/Xk planes.
// Projection: 512x128 = A[512,768] @ Wt_head[128,768]^T, waves 4m x 2n,
//   8x4 16x16x32 frags each, triple-buffer + counted vmcnt(5) (1 blk/CU!).
// Planes: Xq/Xk [512][72] bf16 (pad 8 -> all frag reads at bank BW floor).
// QK: 64 tiles 64x64, wave w owns tiles (it+jt)%8==w (balanced ~4.5 compute).
#define PBUF 40960   // A 32768 + W 8192 per staging buffer
__global__ __launch_bounds__(512) void fused_kernel(
    const bf16* __restrict__ Abf, const bf16* __restrict__ Wt,
    const float* __restrict__ bias,
    const float* __restrict__ Tc, const float* __restrict__ Ts,
    const u64* __restrict__ Mbits, float* __restrict__ out) {
    __shared__ char smem[147456];
    bf16* Xq = (bf16*)smem;                  // [512][72]
    bf16* Xk = (bf16*)(smem + 73728);        // [512][72]

    // XCD chunked swizzle: 192 blocks -> 24 consecutive z per XCD (2 full b's)
    const int zo = blockIdx.x;
    const int z  = (zo & 7) * 24 + (zo >> 3);
    const int b  = z / Tsz, th = z % Tsz;

    const int tid  = threadIdx.x;
    const int wave = tid >> 6, lane = tid & 63;
    const int l15 = lane & 15, hi = lane >> 4;
    const int wm = wave >> 1, wn = wave & 1;

    const bf16* Ab = Abf + (size_t)b * Lsz * Dsz;      // A panel for batch b
    const bf16* Wb = Wt + (size_t)th * 128 * Dsz;      // head slice of Wt
    const int sc8 = (lane & 3) * 8;                     // k-chunk (elems)
    const int lq  = lane >> 2;                          // row-within-16 group

    // ---------- phase 1: projection ----------
    f32x4 acc[8][4] = {};

#define PSTAGE(buf, kk)                                                         \
    do {                                                                        \
        bf16* As = (bf16*)(smem + (buf) * PBUF);                                \
        bf16* Ws = (bf16*)(smem + (buf) * PBUF + 32768);                        \
        _Pragma("unroll")                                                       \
        for (int i = 0; i < 4; ++i) {                                           \
            int ra = wave * 64 + i * 16 + lq;                                   \
            load_lds16(Ab + (size_t)ra * Dsz + (kk) + sc8, As + ra * 32 + sc8); \
        }                                                                       \
        int rw = wave * 16 + lq;                                                \
        load_lds16(Wb + (size_t)rw * Dsz + (kk) + sc8, Ws + rw * 32 + sc8);     \
    } while (0)

    PSTAGE(0, 0);
    PSTAGE(1, 32);
    asm volatile("s_waitcnt vmcnt(5)" ::: "memory");
    __builtin_amdgcn_s_barrier();

    int cur = 0;
    for (int t = 0; t < 24; ++t) {                       // 24 K-steps of 32
        int stg = cur + 2; if (stg >= 3) stg -= 3;
        if (t + 2 < 24) PSTAGE(stg, (t + 2) * 32);

        const char* As = smem + cur * PBUF;
        const char* Ws = smem + cur * PBUF + 32768;
        bf16x8 af[8], bw[4];
#pragma unroll
        for (int mf = 0; mf < 8; ++mf)
            af[mf] = *(const bf16x8*)(As + (wm * 128 + mf * 16 + l15) * 64 + hi * 16);
#pragma unroll
        for (int nf = 0; nf < 4; ++nf)
            bw[nf] = *(const bf16x8*)(Ws + (wn * 64 + nf * 16 + l15) * 64 + hi * 16);
#pragma unroll
        for (int mf = 0; mf < 8; ++mf)
#pragma unroll
            for (int nf = 0; nf < 4; ++nf)
                acc[mf][nf] = __builtin_amdgcn_mfma_f32_16x16x32_bf16(af[mf], bw[nf], acc[mf][nf], 0, 0, 0);

        if (t + 1 < 24) {
            if (t + 2 < 24) asm volatile("s_waitcnt vmcnt(5)" ::: "memory");
            else            asm volatile("s_waitcnt vmcnt(0)" ::: "memory");
            __builtin_amdgcn_s_barrier();
        }
        cur = cur + 1; if (cur >= 3) cur -= 3;
    }
#undef PSTAGE
    __syncthreads();    // staging dead; smem becomes Xq/Xk planes

    // ---------- phase 2: acc (+bias) -> q/k planes ----------
    // C/D: col=l15, row=hi*4+r. head col c: even->q, odd->k, a=c>>1.
    {
        const int r0 = hi * 4;
#pragma unroll
        for (int nf = 0; nf < 4; ++nf) {
            const int c = wn * 64 + nf * 16 + l15;
            const float bv = bias[th * 128 + c];
            bf16* P = (c & 1) ? Xk : Xq;
            const int a = c >> 1;
#pragma unroll
            for (int mf = 0; mf < 8; ++mf) {
                const int rw = wm * 128 + mf * 16 + r0;
#pragma unroll
                for (int r = 0; r < 4; ++r)
                    P[(rw + r) * 72 + a] = (bf16)(acc[mf][nf][r] + bv);
            }
        }
    }
    __syncthreads();

    // ---------- phase 3: rope in place (thread = row l) ----------
    {
        const int l = tid;
        const float* tc = Tc + l * 64;
        const float* ts = Ts + l * 64;
#pragma unroll
        for (int p = 0; p < 2; ++p) {
            bf16* P = p ? Xk : Xq;
            float v[64];
#pragma unroll
            for (int c8 = 0; c8 < 8; ++c8) {
                bf16x8 x = *(const bf16x8*)(P + l * 72 + c8 * 8);
#pragma unroll
                for (int j = 0; j < 8; ++j) v[c8 * 8 + j] = (float)x[j];
            }
#pragma unroll
            for (int c8 = 0; c8 < 8; ++c8) {
                bf16x8 o;
#pragma unroll
                for (int j = 0; j < 8; ++j) {
                    const int a  = c8 * 8 + j;
                    const int a2 = (a < 32) ? (2 * a + 1) : (2 * (a - 32));
                    const float sg = (a < 32) ? -1.f : 1.f;
                    o[j] = (bf16)(v[a] * tc[a] + sg * v[a2] * ts[a]);
                }
                *(bf16x8*)(P + l * 72 + c8 * 8) = o;
            }
        }
    }
    __syncthreads();

    // ---------- phase 4: QK^T + mask, 64 tiles, wave-balanced ----------
    float* ob = out + (size_t)z * Lsz * Lsz;
    const u64* mb = Mbits + b * 8;
#pragma unroll
    for (int s = 0; s < 8; ++s) {
        const int it = s, jt = (wave - s) & 7;
        const int i0 = it * 64, j0 = jt * 64;
        if (jt >= it) {
            const u64 jb = mb[jt], ib = mb[it];
            bf16x8 k0[4], k1[4];
#pragma unroll
            for (int ct = 0; ct < 4; ++ct) {
                const int jr = j0 + ct * 16 + l15;
                k0[ct] = *(const bf16x8*)(Xk + jr * 72 + hi * 8);
                k1[ct] = *(const bf16x8*)(Xk + jr * 72 + 32 + hi * 8);
            }
#pragma unroll
            for (int is = 0; is < 4; ++is) {
                const int ir = i0 + is * 16 + l15;
                bf16x8 q0 = *(const bf16x8*)(Xq + ir * 72 + hi * 8);
                bf16x8 q1 = *(const bf16x8*)(Xq + ir * 72 + 32 + hi * 8);
                f32x4 a4[4] = {};
#pragma unroll
                for (int ct = 0; ct < 4; ++ct) {
                    a4[ct] = __builtin_amdgcn_mfma_f32_16x16x32_bf16(k0[ct], q0, a4[ct], 0, 0, 0);
                    a4[ct] = __builtin_amdgcn_mfma_f32_16x16x32_bf16(k1[ct], q1, a4[ct], 0, 0, 0);
                }
                const bool mi = (ib >> (is * 16 + l15)) & 1;
#pragma unroll
                for (int ct = 0; ct < 4; ++ct) {
                    const int jbase = ct * 16 + hi * 4;
                    float4 vv;
#pragma unroll
                    for (int r = 0; r < 4; ++r) {
                        const int j = j0 + jbase + r;
                        const bool keep = mi && ((jb >> (jbase + r)) & 1) && (ir <= j);
                        vv[r] = keep ? a4[ct][r] : -1e12f;
                    }
                    *(float4*)(ob + (size_t)ir * Lsz + j0 + jbase) = vv;
                }
            }
        } else {
            float4 f; f.x = f.y = f.z = f.w = -1e12f;
#pragma unroll
            for (int is = 0; is < 4; ++is) {
                const int ir = i0 + is * 16 + l15;
#pragma unroll
                for (int cc = 0; cc < 4; ++cc)
                    *(float4*)(ob + (size_t)ir * Lsz + j0 + hi * 16 + cc * 4) = f;
            }
        }
    }
}

extern "C" void kernel_launch(void* const* d_in, const int* in_sizes, int n_in,
                              void* d_out, int out_size, void* d_ws, size_t ws_size,
                              hipStream_t stream) {
    const float* in_f  = (const float*)d_in[0];
    const int*   amask = (const int*)d_in[1];
    const float* W     = (const float*)d_in[2];
    const float* bias  = (const float*)d_in[3];
    float* out = (float*)d_out;

    char* ws = (char*)d_ws;
    bf16*  Abf   = (bf16*)ws;                                // 12,582,912 B
    bf16*  Wt    = (bf16*)(ws + 12582912);                   //  2,359,296 B
    float* Tc    = (float*)(ws + 14942208);                  //    131,072 B
    float* Ts    = (float*)(ws + 15073280);                  //    131,072 B
    u64*   Mbits = (u64*)(ws + 15204352);                    //      1,024 B

    prep_kernel<<<6880, 256, 0, stream>>>(in_f, W, amask, Abf, Wt, Tc, Ts, Mbits);
    fused_kernel<<<Bsz * Tsz, 512, 0, stream>>>(Abf, Wt, bias, Tc, Ts, Mbits, out);
}